// Round 1
// baseline (492.925 us; speedup 1.0000x reference)
//
#include <hip/hip_runtime.h>
#include <math.h>

// Problem constants (B,C,H,W)=(8,256,64,64); NH=NP=4, d=64, Nq=4096.
namespace {
constexpr int kB = 8;
constexpr int kC = 256;
constexpr int kH = 64;
constexpr int kW = 64;
constexpr int kNq = kH * kW;          // 4096
constexpr int kM = kB * kNq;          // 32768 rows for all GEMMs
}  // namespace

// -----------------------------------------------------------------------------
// K1: transpose (B,C,Nq)->(B,Nq,C) + LayerNorm (+ optional sinusoidal qpos).
// One block = 1 batch x 32 queries x all 256 channels. LDS tile padded to 33
// so load (row-contig), reduce (col-contig) and write (row stride 33) phases
// are all bank-conflict-free.
// -----------------------------------------------------------------------------
__global__ __launch_bounds__(256)
void ln_transpose_kernel(const float* __restrict__ X, const float* __restrict__ gam,
                         const float* __restrict__ beta, const float* __restrict__ ps,
                         float* __restrict__ Out, int do_qpos) {
  __shared__ float tile[256][33];
  __shared__ float psum[8][32];
  __shared__ float psq[8][32];
  __shared__ float mean_s[32];
  __shared__ float rstd_s[32];

  const int blk = blockIdx.x;
  const int b = blk >> 7;               // 128 blocks per batch (4096/32)
  const int n0 = (blk & 127) * 32;
  const int tid = threadIdx.x;
  const float* Xb = X + (size_t)b * kC * kNq;

  // load: lanes 0..31 -> 32 contiguous n for channel c (128B segments)
  for (int i = tid; i < 256 * 32; i += 256) {
    const int c = i >> 5, nn = i & 31;
    tile[c][nn] = Xb[(size_t)c * kNq + n0 + nn];
  }
  __syncthreads();

  // per-query mean/var: 8 channel-groups of 32
  {
    const int nn = tid & 31, cg = tid >> 5;
    float s = 0.f, sq = 0.f;
#pragma unroll
    for (int cc = 0; cc < 32; ++cc) {
      const float v = tile[cg * 32 + cc][nn];
      s += v;
      sq += v * v;
    }
    psum[cg][nn] = s;
    psq[cg][nn] = sq;
  }
  __syncthreads();
  if (tid < 32) {
    float S = 0.f, Q = 0.f;
#pragma unroll
    for (int g = 0; g < 8; ++g) {
      S += psum[g][tid];
      Q += psq[g][tid];
    }
    const float m = S * (1.f / 256.f);
    const float v = Q * (1.f / 256.f) - m * m;
    mean_s[tid] = m;
    rstd_s[tid] = rsqrtf(v + 1e-5f);
  }
  __syncthreads();

  // write: thread = channel c, loop over the 32 queries -> coalesced along c
  const int c = tid;
  const float g = gam[c];
  const float bt = beta[c];
  float scale = 0.f, invf = 0.f;
  if (do_qpos) {
    scale = ps[0];
    const int i2 = (c < 128) ? c : (c - 128);
    invf = powf(10000.f, -(float)(2 * i2) * (1.f / 256.f));
  }
  for (int nn = 0; nn < 32; ++nn) {
    float val = (tile[c][nn] - mean_s[nn]) * rstd_s[nn] * g + bt;
    if (do_qpos) {
      const float a = (float)(n0 + nn) * invf;
      val += ((c < 128) ? sinf(a) : cosf(a)) * scale;
    }
    Out[((size_t)b * kNq + n0 + nn) * kC + c] = val;
  }
}

// -----------------------------------------------------------------------------
// K2: D[m][n] = A[m][:] . Wm[:][n] + bias[n]   (M=32768, N=256, K=256, fp32)
// 64x64 tile, 256 threads, 4x4 accum per thread, K-chunks of 32.
// -----------------------------------------------------------------------------
__global__ __launch_bounds__(256)
void gemm_bias_kernel(const float* __restrict__ A, const float* __restrict__ Wm,
                      const float* __restrict__ bias, float* __restrict__ D) {
  __shared__ float As[64][33];
  __shared__ float Ws[32][64];
  const int m0 = blockIdx.x * 64;
  const int n0 = blockIdx.y * 64;
  const int tid = threadIdx.x;
  const int tx = tid & 15, ty = tid >> 4;
  float acc[4][4] = {};

  for (int kk = 0; kk < 256; kk += 32) {
    for (int i = tid; i < 64 * 32; i += 256) {
      const int r = i >> 5, kc = i & 31;
      As[r][kc] = A[(size_t)(m0 + r) * 256 + kk + kc];
    }
    for (int i = tid; i < 32 * 64; i += 256) {
      const int kr = i >> 6, nc = i & 63;
      Ws[kr][nc] = Wm[(size_t)(kk + kr) * 256 + n0 + nc];
    }
    __syncthreads();
#pragma unroll
    for (int k = 0; k < 32; ++k) {
      float a[4], w[4];
#pragma unroll
      for (int i = 0; i < 4; ++i) a[i] = As[ty * 4 + i][k];
#pragma unroll
      for (int j = 0; j < 4; ++j) w[j] = Ws[k][tx * 4 + j];
#pragma unroll
      for (int i = 0; i < 4; ++i)
#pragma unroll
        for (int j = 0; j < 4; ++j) acc[i][j] = fmaf(a[i], w[j], acc[i][j]);
    }
    __syncthreads();
  }
#pragma unroll
  for (int i = 0; i < 4; ++i) {
    const size_t m = (size_t)m0 + ty * 4 + i;
#pragma unroll
    for (int j = 0; j < 4; ++j) {
      const int n = n0 + tx * 4 + j;
      D[m * 256 + n] = acc[i][j] + bias[n];
    }
  }
}

// -----------------------------------------------------------------------------
// K3: RAW[m][0:32] = query @ W_off + b_off ; RAW[m][32:48] = query @ W_att + b_att
// Single 64-row x 48-col (padded to 64) tile per block.
// -----------------------------------------------------------------------------
__global__ __launch_bounds__(256)
void gemm_offatt_kernel(const float* __restrict__ Q, const float* __restrict__ Woff,
                        const float* __restrict__ boff, const float* __restrict__ Watt,
                        const float* __restrict__ batt, float* __restrict__ RAW) {
  __shared__ float As[64][33];
  __shared__ float Ws[32][64];
  const int m0 = blockIdx.x * 64;
  const int tid = threadIdx.x;
  const int tx = tid & 15, ty = tid >> 4;
  float acc[4][4] = {};

  for (int kk = 0; kk < 256; kk += 32) {
    for (int i = tid; i < 64 * 32; i += 256) {
      const int r = i >> 5, kc = i & 31;
      As[r][kc] = Q[(size_t)(m0 + r) * 256 + kk + kc];
    }
    for (int i = tid; i < 32 * 64; i += 256) {
      const int kr = i >> 6, nc = i & 63;
      const int k = kk + kr;
      float w = 0.f;
      if (nc < 32) w = Woff[(size_t)k * 32 + nc];
      else if (nc < 48) w = Watt[(size_t)k * 16 + (nc - 32)];
      Ws[kr][nc] = w;
    }
    __syncthreads();
#pragma unroll
    for (int k = 0; k < 32; ++k) {
      float a[4], w[4];
#pragma unroll
      for (int i = 0; i < 4; ++i) a[i] = As[ty * 4 + i][k];
#pragma unroll
      for (int j = 0; j < 4; ++j) w[j] = Ws[k][tx * 4 + j];
#pragma unroll
      for (int i = 0; i < 4; ++i)
#pragma unroll
        for (int j = 0; j < 4; ++j) acc[i][j] = fmaf(a[i], w[j], acc[i][j]);
    }
    __syncthreads();
  }
#pragma unroll
  for (int i = 0; i < 4; ++i) {
    const size_t m = (size_t)m0 + ty * 4 + i;
#pragma unroll
    for (int j = 0; j < 4; ++j) {
      const int n = tx * 4 + j;
      if (n < 48) {
        const float bias = (n < 32) ? boff[n] : batt[n - 32];
        RAW[m * 48 + n] = acc[i][j] + bias;
      }
    }
  }
}

// -----------------------------------------------------------------------------
// K4: softmax over the 4 points + bilinear sampling from V, per (b,q,head).
// Block = 256 threads = 4 waves; wave h handles head h, lane j = channel j.
// V gathers are 256B-coalesced per corner row. Zero padding == skip OOB corner.
// px = w + off_x exactly (W=64 cancels the offset normalizer); py = h + off_y.
// -----------------------------------------------------------------------------
__global__ __launch_bounds__(256)
void sample_kernel(const float* __restrict__ RAW, const float* __restrict__ V,
                   float* __restrict__ AO) {
  const int m = blockIdx.x;            // b*4096 + q
  const int b = m >> 12;
  const int q = m & 4095;
  const int h = threadIdx.x >> 6;      // head
  const int j = threadIdx.x & 63;      // channel within head
  const int wq = q & 63;               // pixel x
  const int hq = q >> 6;               // pixel y

  const float* raw = RAW + (size_t)m * 48;
  // softmax over the 4 attention logits of this head
  const float l0 = raw[32 + h * 4 + 0];
  const float l1 = raw[32 + h * 4 + 1];
  const float l2 = raw[32 + h * 4 + 2];
  const float l3 = raw[32 + h * 4 + 3];
  const float mx = fmaxf(fmaxf(l0, l1), fmaxf(l2, l3));
  const float e0 = expf(l0 - mx), e1 = expf(l1 - mx), e2 = expf(l2 - mx), e3 = expf(l3 - mx);
  const float inv = 1.f / (e0 + e1 + e2 + e3);
  const float att[4] = {e0 * inv, e1 * inv, e2 * inv, e3 * inv};

  const float* vb = V + (size_t)b * kNq * kC + h * 64 + j;
  float acc = 0.f;
#pragma unroll
  for (int p = 0; p < 4; ++p) {
    const float ox = raw[h * 8 + p * 2 + 0];
    const float oy = raw[h * 8 + p * 2 + 1];
    const float px = (float)wq + ox;
    const float py = (float)hq + oy;
    const float fx = floorf(px), fy = floorf(py);
    const float wx = px - fx, wy = py - fy;
    const int x0 = (int)fx, y0 = (int)fy;
    float sv = 0.f;
    {
      const int xx = x0, yy = y0;
      if (xx >= 0 && xx < 64 && yy >= 0 && yy < 64)
        sv += (1.f - wx) * (1.f - wy) * vb[(size_t)(yy * 64 + xx) * kC];
    }
    {
      const int xx = x0 + 1, yy = y0;
      if (xx >= 0 && xx < 64 && yy >= 0 && yy < 64)
        sv += wx * (1.f - wy) * vb[(size_t)(yy * 64 + xx) * kC];
    }
    {
      const int xx = x0, yy = y0 + 1;
      if (xx >= 0 && xx < 64 && yy >= 0 && yy < 64)
        sv += (1.f - wx) * wy * vb[(size_t)(yy * 64 + xx) * kC];
    }
    {
      const int xx = x0 + 1, yy = y0 + 1;
      if (xx >= 0 && xx < 64 && yy >= 0 && yy < 64)
        sv += wx * wy * vb[(size_t)(yy * 64 + xx) * kC];
    }
    acc += att[p] * sv;
  }
  AO[(size_t)m * kC + threadIdx.x] = acc;
}

// -----------------------------------------------------------------------------
// K5: OUT[b][c][q] = AO[m][:] . W_out[:][c] + b_out[c] + x2[b][c][q]
// Same GEMM core; result staged through LDS so the transposed store is
// coalesced along q (and the x2 residual read shares the same address).
// -----------------------------------------------------------------------------
__global__ __launch_bounds__(256)
void gemm_out_kernel(const float* __restrict__ A, const float* __restrict__ Wm,
                     const float* __restrict__ bias, const float* __restrict__ x2,
                     float* __restrict__ OUT) {
  __shared__ float As[64][33];
  __shared__ float Ws[32][64];
  __shared__ float Ds[64][65];
  const int m0 = blockIdx.x * 64;
  const int c0 = blockIdx.y * 64;
  const int tid = threadIdx.x;
  const int tx = tid & 15, ty = tid >> 4;
  float acc[4][4] = {};

  for (int kk = 0; kk < 256; kk += 32) {
    for (int i = tid; i < 64 * 32; i += 256) {
      const int r = i >> 5, kc = i & 31;
      As[r][kc] = A[(size_t)(m0 + r) * 256 + kk + kc];
    }
    for (int i = tid; i < 32 * 64; i += 256) {
      const int kr = i >> 6, nc = i & 63;
      Ws[kr][nc] = Wm[(size_t)(kk + kr) * 256 + c0 + nc];
    }
    __syncthreads();
#pragma unroll
    for (int k = 0; k < 32; ++k) {
      float a[4], w[4];
#pragma unroll
      for (int i = 0; i < 4; ++i) a[i] = As[ty * 4 + i][k];
#pragma unroll
      for (int j = 0; j < 4; ++j) w[j] = Ws[k][tx * 4 + j];
#pragma unroll
      for (int i = 0; i < 4; ++i)
#pragma unroll
        for (int j = 0; j < 4; ++j) acc[i][j] = fmaf(a[i], w[j], acc[i][j]);
    }
    __syncthreads();
  }
  // stage (c_local, q_local) tile for coalesced transposed write
#pragma unroll
  for (int i = 0; i < 4; ++i)
#pragma unroll
    for (int j = 0; j < 4; ++j) Ds[tx * 4 + j][ty * 4 + i] = acc[i][j];
  __syncthreads();

  const int b = m0 >> 12;
  const int q0 = m0 & 4095;
  for (int i = tid; i < 64 * 64; i += 256) {
    const int cl = i >> 6, ql = i & 63;
    const size_t o = ((size_t)b * kC + c0 + cl) * kNq + q0 + ql;
    OUT[o] = Ds[cl][ql] + bias[c0 + cl] + x2[o];
  }
}

// -----------------------------------------------------------------------------
extern "C" void kernel_launch(void* const* d_in, const int* in_sizes, int n_in,
                              void* d_out, int out_size, void* d_ws, size_t ws_size,
                              hipStream_t stream) {
  const float* x1 = (const float*)d_in[0];
  const float* x2 = (const float*)d_in[1];
  const float* ln1_g = (const float*)d_in[2];
  const float* ln1_b = (const float*)d_in[3];
  const float* ln2_g = (const float*)d_in[4];
  const float* ln2_b = (const float*)d_in[5];
  const float* pos_scale = (const float*)d_in[6];
  const float* W_off = (const float*)d_in[7];
  const float* b_off = (const float*)d_in[8];
  const float* W_att = (const float*)d_in[9];
  const float* b_att = (const float*)d_in[10];
  const float* W_val = (const float*)d_in[11];
  const float* b_val = (const float*)d_in[12];
  const float* W_out = (const float*)d_in[13];
  const float* b_out = (const float*)d_in[14];
  float* out = (float*)d_out;

  float* ws = (float*)d_ws;
  const size_t plane = (size_t)kM * kC;  // 8,388,608 floats
  float* Q = ws;                // query (B,Nq,C)
  float* LN2 = ws + plane;      // LN(x2^T); reused as attn-out after value GEMM
  float* V = ws + 2 * plane;    // value (B,Nq,C)
  float* RAW = ws + 3 * plane;  // (M,48): 32 offsets + 16 logits

  // 1) LN + transpose (+qpos for query path)
  ln_transpose_kernel<<<1024, 256, 0, stream>>>(x1, ln1_g, ln1_b, pos_scale, Q, 1);
  ln_transpose_kernel<<<1024, 256, 0, stream>>>(x2, ln2_g, ln2_b, pos_scale, LN2, 0);

  // 2) value = LN2 @ W_val + b_val
  gemm_bias_kernel<<<dim3(kM / 64, 4), 256, 0, stream>>>(LN2, W_val, b_val, V);

  // 3) offsets + attention logits
  gemm_offatt_kernel<<<kM / 64, 256, 0, stream>>>(Q, W_off, b_off, W_att, b_att, RAW);

  // 4) softmax + bilinear sampling -> AO (reuses LN2 buffer)
  sample_kernel<<<kM, 256, 0, stream>>>(RAW, V, LN2);

  // 5) out-proj + bias + residual, transposed store
  gemm_out_kernel<<<dim3(kM / 64, 4), 256, 0, stream>>>(LN2, W_out, b_out, x2, out);
}

// Round 2
// 305.518 us; speedup vs baseline: 1.6134x; 1.6134x over previous
//
#include <hip/hip_runtime.h>
#include <math.h>

// (B,C,H,W)=(8,256,64,64); NH=NP=4, d=64, Nq=4096, M=B*Nq=32768.
namespace {
constexpr int kC = 256;
constexpr int kNq = 4096;
constexpr int kM = 32768;
}

typedef __attribute__((ext_vector_type(8))) short short8;
typedef __attribute__((ext_vector_type(4))) float f32x4;

__device__ inline unsigned short f2bf(float f) {
  union { float f; unsigned u; } v; v.f = f;
  unsigned r = (v.u + 0x7FFFu + ((v.u >> 16) & 1u)) >> 16;  // RNE
  return (unsigned short)r;
}
__device__ inline float bf2f(unsigned short h) {
  union { unsigned u; float f; } v; v.u = ((unsigned)h) << 16; return v.f;
}

// -----------------------------------------------------------------------------
// K0: weight prep — convert to bf16 and transpose so every MFMA operand is
// row-major in K (contiguous-K fragments -> ds_read_b128).
// WvT[n][k]=W_val[k][n]; WoT[c][k]=W_out[k][c]; WoaT[j][k]= j<32 ? W_off[k][j]
// : j<48 ? W_att[k][j-32] : 0.
// -----------------------------------------------------------------------------
__global__ __launch_bounds__(256)
void prep_weights_kernel(const float* __restrict__ Wv, const float* __restrict__ Wo,
                         const float* __restrict__ Woff, const float* __restrict__ Watt,
                         unsigned short* __restrict__ WvT, unsigned short* __restrict__ WoT,
                         unsigned short* __restrict__ WoaT) {
  const int i = blockIdx.x * 256 + threadIdx.x;  // grid 256 blocks -> i < 65536
  {
    const int n = i >> 8, k = i & 255;
    WvT[i] = f2bf(Wv[k * 256 + n]);
    WoT[i] = f2bf(Wo[k * 256 + n]);
  }
  if (i < 16384) {
    const int j = i >> 8, k = i & 255;
    float v = 0.f;
    if (j < 32) v = Woff[k * 32 + j];
    else if (j < 48) v = Watt[k * 16 + (j - 32)];
    WoaT[i] = f2bf(v);
  }
}

// -----------------------------------------------------------------------------
// K1: transpose (B,C,Nq)->(B,Nq,C) + LayerNorm (+ optional qpos), bf16 out.
// -----------------------------------------------------------------------------
__global__ __launch_bounds__(256)
void ln_transpose_kernel(const float* __restrict__ X, const float* __restrict__ gam,
                         const float* __restrict__ beta, const float* __restrict__ ps,
                         unsigned short* __restrict__ Out, int do_qpos) {
  __shared__ float tile[256][33];
  __shared__ float psum[8][32];
  __shared__ float psq[8][32];
  __shared__ float mean_s[32];
  __shared__ float rstd_s[32];

  const int blk = blockIdx.x;
  const int b = blk >> 7;
  const int n0 = (blk & 127) * 32;
  const int tid = threadIdx.x;
  const float* Xb = X + (size_t)b * kC * kNq;

  for (int i = tid; i < 256 * 32; i += 256) {
    const int c = i >> 5, nn = i & 31;
    tile[c][nn] = Xb[(size_t)c * kNq + n0 + nn];
  }
  __syncthreads();
  {
    const int nn = tid & 31, cg = tid >> 5;
    float s = 0.f, sq = 0.f;
#pragma unroll
    for (int cc = 0; cc < 32; ++cc) {
      const float v = tile[cg * 32 + cc][nn];
      s += v; sq += v * v;
    }
    psum[cg][nn] = s; psq[cg][nn] = sq;
  }
  __syncthreads();
  if (tid < 32) {
    float S = 0.f, Q = 0.f;
#pragma unroll
    for (int g = 0; g < 8; ++g) { S += psum[g][tid]; Q += psq[g][tid]; }
    const float m = S * (1.f / 256.f);
    const float v = Q * (1.f / 256.f) - m * m;
    mean_s[tid] = m;
    rstd_s[tid] = rsqrtf(v + 1e-5f);
  }
  __syncthreads();

  const int c = tid;
  const float g = gam[c];
  const float bt = beta[c];
  float scale = 0.f, invf = 0.f;
  if (do_qpos) {
    scale = ps[0];
    const int i2 = (c < 128) ? c : (c - 128);
    invf = powf(10000.f, -(float)(2 * i2) * (1.f / 256.f));
  }
  for (int nn = 0; nn < 32; ++nn) {
    float val = (tile[c][nn] - mean_s[nn]) * rstd_s[nn] * g + bt;
    if (do_qpos) {
      const float a = (float)(n0 + nn) * invf;
      val += ((c < 128) ? sinf(a) : cosf(a)) * scale;
    }
    Out[((size_t)b * kNq + n0 + nn) * kC + c] = f2bf(val);
  }
}

// -----------------------------------------------------------------------------
// MFMA GEMM core pieces. D[i][j] = sum_k P[i0+i][k]*Q[j0+j][k], K=256, bf16.
// 128x128 tile, 4 waves (2x2), each wave 64x64 = 4x4 frags of 16x16x32.
// LDS rows padded to 72 shorts (stride 144B -> bank shift 4 -> <=2-way, free).
// Frag layouts [verified, guide §3]: A/B lane holds [m|n = lane&15][k = quad*8+j];
// C/D: col = lane&15, row = quad*4 + reg.
// -----------------------------------------------------------------------------
__global__ __launch_bounds__(256)
void gemm_val_kernel(const unsigned short* __restrict__ A,   // [kM][256] LN2 bf16
                     const unsigned short* __restrict__ Bt,  // [256][256] WvT bf16
                     const float* __restrict__ bias,
                     unsigned short* __restrict__ V) {       // [kM][256] bf16
  __shared__ unsigned short As[128][72];
  __shared__ unsigned short Bs[128][72];
  const int m0 = blockIdx.x * 128;
  const int n0 = blockIdx.y * 128;
  const int tid = threadIdx.x;
  const int lane = tid & 63, w = tid >> 6;
  const int wm = w >> 1, wn = w & 1;
  const int l15 = lane & 15, quad = lane >> 4;
  f32x4 acc[4][4];
#pragma unroll
  for (int i = 0; i < 4; ++i)
#pragma unroll
    for (int j = 0; j < 4; ++j) acc[i][j] = (f32x4){0.f, 0.f, 0.f, 0.f};

  for (int kk = 0; kk < 256; kk += 64) {
    for (int i = tid; i < 1024; i += 256) {
      const int r = i >> 3, cc = (i & 7) * 8;
      *(short8*)&As[r][cc] = *(const short8*)&A[(size_t)(m0 + r) * 256 + kk + cc];
      *(short8*)&Bs[r][cc] = *(const short8*)&Bt[(size_t)(n0 + r) * 256 + kk + cc];
    }
    __syncthreads();
#pragma unroll
    for (int s = 0; s < 2; ++s) {
      short8 af[4], bfr[4];
#pragma unroll
      for (int t = 0; t < 4; ++t) af[t] = *(const short8*)&As[wm * 64 + t * 16 + l15][s * 32 + quad * 8];
#pragma unroll
      for (int t = 0; t < 4; ++t) bfr[t] = *(const short8*)&Bs[wn * 64 + t * 16 + l15][s * 32 + quad * 8];
#pragma unroll
      for (int i = 0; i < 4; ++i)
#pragma unroll
        for (int j = 0; j < 4; ++j)
          acc[i][j] = __builtin_amdgcn_mfma_f32_16x16x32_bf16(af[i], bfr[j], acc[i][j], 0, 0, 0);
    }
    __syncthreads();
  }
#pragma unroll
  for (int i = 0; i < 4; ++i)
#pragma unroll
    for (int j = 0; j < 4; ++j) {
      const int n = n0 + wn * 64 + j * 16 + l15;
      const float bn = bias[n];
#pragma unroll
      for (int r = 0; r < 4; ++r) {
        const int m = m0 + wm * 64 + i * 16 + quad * 4 + r;
        V[(size_t)m * 256 + n] = f2bf(acc[i][j][r] + bn);
      }
    }
}

// Out-projection computed transposed: D[c][q'] = sum_k WoT[c][k]*AO[m][k].
// Store is contiguous in q -> coalesced OUT write + x2 residual read.
__global__ __launch_bounds__(256)
void gemm_out_kernel(const unsigned short* __restrict__ Wt,  // [256][256] WoT bf16
                     const unsigned short* __restrict__ AO,  // [kM][256] bf16
                     const float* __restrict__ bias, const float* __restrict__ x2,
                     float* __restrict__ OUT) {
  __shared__ unsigned short As[128][72];  // WoT rows (c)
  __shared__ unsigned short Bs[128][72];  // AO rows (m)
  const int c0 = blockIdx.y * 128;
  const int q0 = blockIdx.x * 128;  // AO row tile
  const int tid = threadIdx.x;
  const int lane = tid & 63, w = tid >> 6;
  const int wm = w >> 1, wn = w & 1;
  const int l15 = lane & 15, quad = lane >> 4;
  f32x4 acc[4][4];
#pragma unroll
  for (int i = 0; i < 4; ++i)
#pragma unroll
    for (int j = 0; j < 4; ++j) acc[i][j] = (f32x4){0.f, 0.f, 0.f, 0.f};

  for (int kk = 0; kk < 256; kk += 64) {
    for (int i = tid; i < 1024; i += 256) {
      const int r = i >> 3, cc = (i & 7) * 8;
      *(short8*)&As[r][cc] = *(const short8*)&Wt[(size_t)(c0 + r) * 256 + kk + cc];
      *(short8*)&Bs[r][cc] = *(const short8*)&AO[(size_t)(q0 + r) * 256 + kk + cc];
    }
    __syncthreads();
#pragma unroll
    for (int s = 0; s < 2; ++s) {
      short8 af[4], bfr[4];
#pragma unroll
      for (int t = 0; t < 4; ++t) af[t] = *(const short8*)&As[wm * 64 + t * 16 + l15][s * 32 + quad * 8];
#pragma unroll
      for (int t = 0; t < 4; ++t) bfr[t] = *(const short8*)&Bs[wn * 64 + t * 16 + l15][s * 32 + quad * 8];
#pragma unroll
      for (int i = 0; i < 4; ++i)
#pragma unroll
        for (int j = 0; j < 4; ++j)
          acc[i][j] = __builtin_amdgcn_mfma_f32_16x16x32_bf16(af[i], bfr[j], acc[i][j], 0, 0, 0);
    }
    __syncthreads();
  }
  const int b = q0 >> 12;       // tile rows share one batch (q0 multiple of 128)
  const int qb = q0 & 4095;
#pragma unroll
  for (int i = 0; i < 4; ++i) {
#pragma unroll
    for (int r = 0; r < 4; ++r) {
      const int c = c0 + wm * 64 + i * 16 + quad * 4 + r;
      const float bc = bias[c];
      const size_t rowbase = ((size_t)b * 256 + c) * 4096 + qb;
#pragma unroll
      for (int j = 0; j < 4; ++j) {
        const int q = wn * 64 + j * 16 + l15;
        OUT[rowbase + q] = acc[i][j][r] + bc + x2[rowbase + q];
      }
    }
  }
}

// off+att GEMM: tile 128x64 (N=48 padded to 64 via zeroed WoaT rows).
__global__ __launch_bounds__(256)
void gemm_offatt_kernel(const unsigned short* __restrict__ Q,    // [kM][256] bf16
                        const unsigned short* __restrict__ Wt,   // [64][256] WoaT bf16
                        const float* __restrict__ boff, const float* __restrict__ batt,
                        float* __restrict__ RAW) {               // [kM][48]
  __shared__ unsigned short As[128][72];
  __shared__ unsigned short Bs[64][72];
  const int m0 = blockIdx.x * 128;
  const int tid = threadIdx.x;
  const int lane = tid & 63, w = tid >> 6;
  const int wm = w >> 1, wn = w & 1;  // wave: 64 rows x 32 cols
  const int l15 = lane & 15, quad = lane >> 4;
  f32x4 acc[4][2];
#pragma unroll
  for (int i = 0; i < 4; ++i) { acc[i][0] = (f32x4){0.f,0.f,0.f,0.f}; acc[i][1] = (f32x4){0.f,0.f,0.f,0.f}; }

  for (int kk = 0; kk < 256; kk += 64) {
    for (int i = tid; i < 1024; i += 256) {
      const int r = i >> 3, cc = (i & 7) * 8;
      *(short8*)&As[r][cc] = *(const short8*)&Q[(size_t)(m0 + r) * 256 + kk + cc];
    }
    for (int i = tid; i < 512; i += 256) {
      const int r = i >> 3, cc = (i & 7) * 8;
      *(short8*)&Bs[r][cc] = *(const short8*)&Wt[(size_t)r * 256 + kk + cc];
    }
    __syncthreads();
#pragma unroll
    for (int s = 0; s < 2; ++s) {
      short8 af[4], bfr[2];
#pragma unroll
      for (int t = 0; t < 4; ++t) af[t] = *(const short8*)&As[wm * 64 + t * 16 + l15][s * 32 + quad * 8];
#pragma unroll
      for (int t = 0; t < 2; ++t) bfr[t] = *(const short8*)&Bs[wn * 32 + t * 16 + l15][s * 32 + quad * 8];
#pragma unroll
      for (int i = 0; i < 4; ++i)
#pragma unroll
        for (int j = 0; j < 2; ++j)
          acc[i][j] = __builtin_amdgcn_mfma_f32_16x16x32_bf16(af[i], bfr[j], acc[i][j], 0, 0, 0);
    }
    __syncthreads();
  }
#pragma unroll
  for (int i = 0; i < 4; ++i)
#pragma unroll
    for (int j = 0; j < 2; ++j) {
      const int n = wn * 32 + j * 16 + l15;
      if (n < 48) {
        const float bn = (n < 32) ? boff[n] : batt[n - 32];
#pragma unroll
        for (int r = 0; r < 4; ++r) {
          const int m = m0 + wm * 64 + i * 16 + quad * 4 + r;
          RAW[(size_t)m * 48 + n] = acc[i][j][r] + bn;
        }
      }
    }
}

// -----------------------------------------------------------------------------
// K4: softmax(4) + bilinear sampling. Block = (b,q); wave h = head; lane = chan.
// V and AO in bf16 (halves gather + store traffic).
// -----------------------------------------------------------------------------
__global__ __launch_bounds__(256)
void sample_kernel(const float* __restrict__ RAW, const unsigned short* __restrict__ V,
                   unsigned short* __restrict__ AO) {
  const int m = blockIdx.x;
  const int b = m >> 12;
  const int q = m & 4095;
  const int h = threadIdx.x >> 6;
  const int j = threadIdx.x & 63;
  const int wq = q & 63;
  const int hq = q >> 6;

  const float* raw = RAW + (size_t)m * 48;
  const float l0 = raw[32 + h * 4 + 0];
  const float l1 = raw[32 + h * 4 + 1];
  const float l2 = raw[32 + h * 4 + 2];
  const float l3 = raw[32 + h * 4 + 3];
  const float mx = fmaxf(fmaxf(l0, l1), fmaxf(l2, l3));
  const float e0 = expf(l0 - mx), e1 = expf(l1 - mx), e2 = expf(l2 - mx), e3 = expf(l3 - mx);
  const float inv = 1.f / (e0 + e1 + e2 + e3);
  const float att[4] = {e0 * inv, e1 * inv, e2 * inv, e3 * inv};

  const unsigned short* vb = V + (size_t)b * kNq * kC + h * 64 + j;
  float acc = 0.f;
#pragma unroll
  for (int p = 0; p < 4; ++p) {
    const float ox = raw[h * 8 + p * 2 + 0];
    const float oy = raw[h * 8 + p * 2 + 1];
    const float px = (float)wq + ox;   // W=64 cancels the offset normalizer
    const float py = (float)hq + oy;
    const float fx = floorf(px), fy = floorf(py);
    const float wx = px - fx, wy = py - fy;
    const int x0 = (int)fx, y0 = (int)fy;
    float sv = 0.f;
    if (x0 >= 0 && x0 < 64 && y0 >= 0 && y0 < 64)
      sv += (1.f - wx) * (1.f - wy) * bf2f(vb[(size_t)(y0 * 64 + x0) * kC]);
    if (x0 + 1 >= 0 && x0 + 1 < 64 && y0 >= 0 && y0 < 64)
      sv += wx * (1.f - wy) * bf2f(vb[(size_t)(y0 * 64 + x0 + 1) * kC]);
    if (x0 >= 0 && x0 < 64 && y0 + 1 >= 0 && y0 + 1 < 64)
      sv += (1.f - wx) * wy * bf2f(vb[(size_t)((y0 + 1) * 64 + x0) * kC]);
    if (x0 + 1 >= 0 && x0 + 1 < 64 && y0 + 1 >= 0 && y0 + 1 < 64)
      sv += wx * wy * bf2f(vb[(size_t)((y0 + 1) * 64 + x0 + 1) * kC]);
    acc += att[p] * sv;
  }
  AO[(size_t)m * kC + threadIdx.x] = f2bf(acc);
}

// -----------------------------------------------------------------------------
extern "C" void kernel_launch(void* const* d_in, const int* in_sizes, int n_in,
                              void* d_out, int out_size, void* d_ws, size_t ws_size,
                              hipStream_t stream) {
  const float* x1 = (const float*)d_in[0];
  const float* x2 = (const float*)d_in[1];
  const float* ln1_g = (const float*)d_in[2];
  const float* ln1_b = (const float*)d_in[3];
  const float* ln2_g = (const float*)d_in[4];
  const float* ln2_b = (const float*)d_in[5];
  const float* pos_scale = (const float*)d_in[6];
  const float* W_off = (const float*)d_in[7];
  const float* b_off = (const float*)d_in[8];
  const float* W_att = (const float*)d_in[9];
  const float* b_att = (const float*)d_in[10];
  const float* W_val = (const float*)d_in[11];
  const float* b_val = (const float*)d_in[12];
  const float* W_out = (const float*)d_in[13];
  const float* b_out = (const float*)d_in[14];
  float* out = (float*)d_out;

  char* ws = (char*)d_ws;
  const size_t plane2 = (size_t)kM * kC * sizeof(unsigned short);  // 16 MiB
  unsigned short* Qb   = (unsigned short*)(ws);
  unsigned short* LN2b = (unsigned short*)(ws + plane2);
  unsigned short* Vb   = (unsigned short*)(ws + 2 * plane2);
  unsigned short* AOb  = (unsigned short*)(ws + 3 * plane2);
  float* RAW           = (float*)(ws + 4 * plane2);
  unsigned short* WvT  = (unsigned short*)(ws + 4 * plane2 + (size_t)kM * 48 * 4);
  unsigned short* WoT  = WvT + 65536;
  unsigned short* WoaT = WoT + 65536;

  prep_weights_kernel<<<256, 256, 0, stream>>>(W_val, W_out, W_off, W_att, WvT, WoT, WoaT);
  ln_transpose_kernel<<<1024, 256, 0, stream>>>(x1, ln1_g, ln1_b, pos_scale, Qb, 1);
  ln_transpose_kernel<<<1024, 256, 0, stream>>>(x2, ln2_g, ln2_b, pos_scale, LN2b, 0);
  gemm_val_kernel<<<dim3(kM / 128, 2), 256, 0, stream>>>(LN2b, WvT, b_val, Vb);
  gemm_offatt_kernel<<<kM / 128, 256, 0, stream>>>(Qb, WoaT, b_off, b_att, RAW);
  sample_kernel<<<kM, 256, 0, stream>>>(RAW, Vb, AOb);
  gemm_out_kernel<<<dim3(kM / 128, 2), 256, 0, stream>>>(WoT, AOb, b_out, x2, out);
}

// Round 3
// 219.415 us; speedup vs baseline: 2.2465x; 1.3924x over previous
//
#include <hip/hip_runtime.h>
#include <math.h>

// (B,C,H,W)=(8,256,64,64); NH=NP=4, d=64, Nq=4096, M=B*Nq=32768.
namespace {
constexpr int kC = 256;
constexpr int kNq = 4096;
constexpr int kM = 32768;
}

typedef __attribute__((ext_vector_type(8))) short short8;
typedef __attribute__((ext_vector_type(4))) float f32x4;

__device__ inline unsigned short f2bf(float f) {
  union { float f; unsigned u; } v; v.f = f;
  unsigned r = (v.u + 0x7FFFu + ((v.u >> 16) & 1u)) >> 16;  // RNE
  return (unsigned short)r;
}
__device__ inline float bf2f(unsigned short h) {
  union { unsigned u; float f; } v; v.u = ((unsigned)h) << 16; return v.f;
}
__device__ inline float uasf(unsigned u) {
  union { unsigned u; float f; } v; v.u = u; return v.f;
}

// -----------------------------------------------------------------------------
// K0: weight prep — convert to bf16 and transpose so every MFMA operand is
// row-major in K (contiguous-K fragments -> ds_read_b128).
// -----------------------------------------------------------------------------
__global__ __launch_bounds__(256)
void prep_weights_kernel(const float* __restrict__ Wv, const float* __restrict__ Wo,
                         const float* __restrict__ Woff, const float* __restrict__ Watt,
                         unsigned short* __restrict__ WvT, unsigned short* __restrict__ WoT,
                         unsigned short* __restrict__ WoaT) {
  const int i = blockIdx.x * 256 + threadIdx.x;  // grid 256 blocks -> i < 65536
  {
    const int n = i >> 8, k = i & 255;
    WvT[i] = f2bf(Wv[k * 256 + n]);
    WoT[i] = f2bf(Wo[k * 256 + n]);
  }
  if (i < 16384) {
    const int j = i >> 8, k = i & 255;
    float v = 0.f;
    if (j < 32) v = Woff[k * 32 + j];
    else if (j < 48) v = Watt[k * 16 + (j - 32)];
    WoaT[i] = f2bf(v);
  }
}

// -----------------------------------------------------------------------------
// K1: transpose (B,C,Nq)->(B,Nq,C) + LayerNorm (+ optional qpos), bf16 out.
// -----------------------------------------------------------------------------
__global__ __launch_bounds__(256)
void ln_transpose_kernel(const float* __restrict__ X, const float* __restrict__ gam,
                         const float* __restrict__ beta, const float* __restrict__ ps,
                         unsigned short* __restrict__ Out, int do_qpos) {
  __shared__ float tile[256][33];
  __shared__ float psum[8][32];
  __shared__ float psq[8][32];
  __shared__ float mean_s[32];
  __shared__ float rstd_s[32];

  const int blk = blockIdx.x;
  const int b = blk >> 7;
  const int n0 = (blk & 127) * 32;
  const int tid = threadIdx.x;
  const float* Xb = X + (size_t)b * kC * kNq;

  for (int i = tid; i < 256 * 32; i += 256) {
    const int c = i >> 5, nn = i & 31;
    tile[c][nn] = Xb[(size_t)c * kNq + n0 + nn];
  }
  __syncthreads();
  {
    const int nn = tid & 31, cg = tid >> 5;
    float s = 0.f, sq = 0.f;
#pragma unroll
    for (int cc = 0; cc < 32; ++cc) {
      const float v = tile[cg * 32 + cc][nn];
      s += v; sq += v * v;
    }
    psum[cg][nn] = s; psq[cg][nn] = sq;
  }
  __syncthreads();
  if (tid < 32) {
    float S = 0.f, Q = 0.f;
#pragma unroll
    for (int g = 0; g < 8; ++g) { S += psum[g][tid]; Q += psq[g][tid]; }
    const float m = S * (1.f / 256.f);
    const float v = Q * (1.f / 256.f) - m * m;
    mean_s[tid] = m;
    rstd_s[tid] = rsqrtf(v + 1e-5f);
  }
  __syncthreads();

  const int c = tid;
  const float g = gam[c];
  const float bt = beta[c];
  float scale = 0.f, invf = 0.f;
  if (do_qpos) {
    scale = ps[0];
    const int i2 = (c < 128) ? c : (c - 128);
    invf = powf(10000.f, -(float)(2 * i2) * (1.f / 256.f));
  }
  for (int nn = 0; nn < 32; ++nn) {
    float val = (tile[c][nn] - mean_s[nn]) * rstd_s[nn] * g + bt;
    if (do_qpos) {
      const float a = (float)(n0 + nn) * invf;
      val += ((c < 128) ? sinf(a) : cosf(a)) * scale;
    }
    Out[((size_t)b * kNq + n0 + nn) * kC + c] = f2bf(val);
  }
}

// -----------------------------------------------------------------------------
// MFMA GEMM cores (see round-2 comments). 128x128 tile, 4 waves, 16x16x32 bf16.
// -----------------------------------------------------------------------------
__global__ __launch_bounds__(256)
void gemm_val_kernel(const unsigned short* __restrict__ A,   // [kM][256] LN2 bf16
                     const unsigned short* __restrict__ Bt,  // [256][256] WvT bf16
                     const float* __restrict__ bias,
                     unsigned short* __restrict__ V) {       // [kM][256] bf16
  __shared__ unsigned short As[128][72];
  __shared__ unsigned short Bs[128][72];
  const int m0 = blockIdx.x * 128;
  const int n0 = blockIdx.y * 128;
  const int tid = threadIdx.x;
  const int lane = tid & 63, w = tid >> 6;
  const int wm = w >> 1, wn = w & 1;
  const int l15 = lane & 15, quad = lane >> 4;
  f32x4 acc[4][4];
#pragma unroll
  for (int i = 0; i < 4; ++i)
#pragma unroll
    for (int j = 0; j < 4; ++j) acc[i][j] = (f32x4){0.f, 0.f, 0.f, 0.f};

  for (int kk = 0; kk < 256; kk += 64) {
    for (int i = tid; i < 1024; i += 256) {
      const int r = i >> 3, cc = (i & 7) * 8;
      *(short8*)&As[r][cc] = *(const short8*)&A[(size_t)(m0 + r) * 256 + kk + cc];
      *(short8*)&Bs[r][cc] = *(const short8*)&Bt[(size_t)(n0 + r) * 256 + kk + cc];
    }
    __syncthreads();
#pragma unroll
    for (int s = 0; s < 2; ++s) {
      short8 af[4], bfr[4];
#pragma unroll
      for (int t = 0; t < 4; ++t) af[t] = *(const short8*)&As[wm * 64 + t * 16 + l15][s * 32 + quad * 8];
#pragma unroll
      for (int t = 0; t < 4; ++t) bfr[t] = *(const short8*)&Bs[wn * 64 + t * 16 + l15][s * 32 + quad * 8];
#pragma unroll
      for (int i = 0; i < 4; ++i)
#pragma unroll
        for (int j = 0; j < 4; ++j)
          acc[i][j] = __builtin_amdgcn_mfma_f32_16x16x32_bf16(af[i], bfr[j], acc[i][j], 0, 0, 0);
    }
    __syncthreads();
  }
#pragma unroll
  for (int i = 0; i < 4; ++i)
#pragma unroll
    for (int j = 0; j < 4; ++j) {
      const int n = n0 + wn * 64 + j * 16 + l15;
      const float bn = bias[n];
#pragma unroll
      for (int r = 0; r < 4; ++r) {
        const int m = m0 + wm * 64 + i * 16 + quad * 4 + r;
        V[(size_t)m * 256 + n] = f2bf(acc[i][j][r] + bn);
      }
    }
}

// Out-projection computed transposed: D[c][q'] = sum_k WoT[c][k]*AO[m][k].
__global__ __launch_bounds__(256)
void gemm_out_kernel(const unsigned short* __restrict__ Wt,  // [256][256] WoT bf16
                     const unsigned short* __restrict__ AO,  // [kM][256] bf16
                     const float* __restrict__ bias, const float* __restrict__ x2,
                     float* __restrict__ OUT) {
  __shared__ unsigned short As[128][72];  // WoT rows (c)
  __shared__ unsigned short Bs[128][72];  // AO rows (m)
  const int c0 = blockIdx.y * 128;
  const int q0 = blockIdx.x * 128;  // AO row tile
  const int tid = threadIdx.x;
  const int lane = tid & 63, w = tid >> 6;
  const int wm = w >> 1, wn = w & 1;
  const int l15 = lane & 15, quad = lane >> 4;
  f32x4 acc[4][4];
#pragma unroll
  for (int i = 0; i < 4; ++i)
#pragma unroll
    for (int j = 0; j < 4; ++j) acc[i][j] = (f32x4){0.f, 0.f, 0.f, 0.f};

  for (int kk = 0; kk < 256; kk += 64) {
    for (int i = tid; i < 1024; i += 256) {
      const int r = i >> 3, cc = (i & 7) * 8;
      *(short8*)&As[r][cc] = *(const short8*)&Wt[(size_t)(c0 + r) * 256 + kk + cc];
      *(short8*)&Bs[r][cc] = *(const short8*)&AO[(size_t)(q0 + r) * 256 + kk + cc];
    }
    __syncthreads();
#pragma unroll
    for (int s = 0; s < 2; ++s) {
      short8 af[4], bfr[4];
#pragma unroll
      for (int t = 0; t < 4; ++t) af[t] = *(const short8*)&As[wm * 64 + t * 16 + l15][s * 32 + quad * 8];
#pragma unroll
      for (int t = 0; t < 4; ++t) bfr[t] = *(const short8*)&Bs[wn * 64 + t * 16 + l15][s * 32 + quad * 8];
#pragma unroll
      for (int i = 0; i < 4; ++i)
#pragma unroll
        for (int j = 0; j < 4; ++j)
          acc[i][j] = __builtin_amdgcn_mfma_f32_16x16x32_bf16(af[i], bfr[j], acc[i][j], 0, 0, 0);
    }
    __syncthreads();
  }
  const int b = q0 >> 12;
  const int qb = q0 & 4095;
#pragma unroll
  for (int i = 0; i < 4; ++i) {
#pragma unroll
    for (int r = 0; r < 4; ++r) {
      const int c = c0 + wm * 64 + i * 16 + quad * 4 + r;
      const float bc = bias[c];
      const size_t rowbase = ((size_t)b * 256 + c) * 4096 + qb;
#pragma unroll
      for (int j = 0; j < 4; ++j) {
        const int q = wn * 64 + j * 16 + l15;
        OUT[rowbase + q] = acc[i][j][r] + bc + x2[rowbase + q];
      }
    }
  }
}

// off+att GEMM: tile 128x64 (N=48 padded to 64 via zeroed WoaT rows).
__global__ __launch_bounds__(256)
void gemm_offatt_kernel(const unsigned short* __restrict__ Q,    // [kM][256] bf16
                        const unsigned short* __restrict__ Wt,   // [64][256] WoaT bf16
                        const float* __restrict__ boff, const float* __restrict__ batt,
                        float* __restrict__ RAW) {               // [kM][48]
  __shared__ unsigned short As[128][72];
  __shared__ unsigned short Bs[64][72];
  const int m0 = blockIdx.x * 128;
  const int tid = threadIdx.x;
  const int lane = tid & 63, w = tid >> 6;
  const int wm = w >> 1, wn = w & 1;  // wave: 64 rows x 32 cols
  const int l15 = lane & 15, quad = lane >> 4;
  f32x4 acc[4][2];
#pragma unroll
  for (int i = 0; i < 4; ++i) { acc[i][0] = (f32x4){0.f,0.f,0.f,0.f}; acc[i][1] = (f32x4){0.f,0.f,0.f,0.f}; }

  for (int kk = 0; kk < 256; kk += 64) {
    for (int i = tid; i < 1024; i += 256) {
      const int r = i >> 3, cc = (i & 7) * 8;
      *(short8*)&As[r][cc] = *(const short8*)&Q[(size_t)(m0 + r) * 256 + kk + cc];
    }
    for (int i = tid; i < 512; i += 256) {
      const int r = i >> 3, cc = (i & 7) * 8;
      *(short8*)&Bs[r][cc] = *(const short8*)&Wt[(size_t)r * 256 + kk + cc];
    }
    __syncthreads();
#pragma unroll
    for (int s = 0; s < 2; ++s) {
      short8 af[4], bfr[2];
#pragma unroll
      for (int t = 0; t < 4; ++t) af[t] = *(const short8*)&As[wm * 64 + t * 16 + l15][s * 32 + quad * 8];
#pragma unroll
      for (int t = 0; t < 2; ++t) bfr[t] = *(const short8*)&Bs[wn * 32 + t * 16 + l15][s * 32 + quad * 8];
#pragma unroll
      for (int i = 0; i < 4; ++i)
#pragma unroll
        for (int j = 0; j < 2; ++j)
          acc[i][j] = __builtin_amdgcn_mfma_f32_16x16x32_bf16(af[i], bfr[j], acc[i][j], 0, 0, 0);
    }
    __syncthreads();
  }
#pragma unroll
  for (int i = 0; i < 4; ++i)
#pragma unroll
    for (int j = 0; j < 2; ++j) {
      const int n = wn * 32 + j * 16 + l15;
      if (n < 48) {
        const float bn = (n < 32) ? boff[n] : batt[n - 32];
#pragma unroll
        for (int r = 0; r < 4; ++r) {
          const int m = m0 + wm * 64 + i * 16 + quad * 4 + r;
          RAW[(size_t)m * 48 + n] = acc[i][j][r] + bn;
        }
      }
    }
}

// -----------------------------------------------------------------------------
// K4 v2: two-phase sampling. Block = 8 queries of one batch.
// Phase 1 (128 thr): thread = (q,h,p). Computes softmax att, bilinear corner
//   weights (att folded, OOB corner -> weight 0 + clamped index); stores
//   4 idx + 4 wgt per triple to LDS.
// Phase 2 (256 thr): thread = (q, head, 8-channel slice). 16 unconditional
//   uint4 gathers; bf16 pairs unpacked with shift/and; packed short8 store.
// -----------------------------------------------------------------------------
__global__ __launch_bounds__(256)
void sample_kernel(const float* __restrict__ RAW, const unsigned short* __restrict__ V,
                   unsigned short* __restrict__ AO) {
  __shared__ int sidx[128][4];
  __shared__ float swgt[128][4];
  const int m0 = blockIdx.x * 8;
  const int b = m0 >> 12;
  const int tid = threadIdx.x;

  if (tid < 128) {
    const int q_l = tid >> 4, h = (tid >> 2) & 3, p = tid & 3;
    const int m = m0 + q_l;
    const float* raw = RAW + (size_t)m * 48;
    const float l0 = raw[32 + h * 4 + 0];
    const float l1 = raw[32 + h * 4 + 1];
    const float l2 = raw[32 + h * 4 + 2];
    const float l3 = raw[32 + h * 4 + 3];
    const float mx = fmaxf(fmaxf(l0, l1), fmaxf(l2, l3));
    const float e0 = expf(l0 - mx), e1 = expf(l1 - mx), e2 = expf(l2 - mx), e3 = expf(l3 - mx);
    const float lp = (p == 0) ? e0 : (p == 1) ? e1 : (p == 2) ? e2 : e3;
    const float attp = lp / (e0 + e1 + e2 + e3);

    const float ox = raw[h * 8 + p * 2 + 0];
    const float oy = raw[h * 8 + p * 2 + 1];
    const float px = (float)(m & 63) + ox;        // W=64 cancels the normalizer
    const float py = (float)((m >> 6) & 63) + oy;
    const float fx = floorf(px), fy = floorf(py);
    const float wx = px - fx, wy = py - fy;
    const int x0 = (int)fx, y0 = (int)fy;
#pragma unroll
    for (int c = 0; c < 4; ++c) {
      const int dx = c & 1, dy = c >> 1;
      const int xx = x0 + dx, yy = y0 + dy;
      const bool valid = (xx >= 0) & (xx < 64) & (yy >= 0) & (yy < 64);
      const float wc = (dx ? wx : 1.f - wx) * (dy ? wy : 1.f - wy) * attp;
      swgt[tid][c] = valid ? wc : 0.f;
      const int xc = min(max(xx, 0), 63), yc = min(max(yy, 0), 63);
      sidx[tid][c] = yc * 64 + xc;
    }
  }
  __syncthreads();

  const int q_l = tid >> 5, sub = tid & 31;
  const int h = sub >> 3, c8 = (sub & 7) * 8;
  const int trip0 = q_l * 16 + h * 4;
  const unsigned short* vb = V + (size_t)b * kNq * kC + h * 64 + c8;
  float acc[8] = {};
#pragma unroll
  for (int p = 0; p < 4; ++p) {
    const int4 idx = *(const int4*)&sidx[trip0 + p][0];
    const float4 wv = *(const float4*)&swgt[trip0 + p][0];
    const int ia[4] = {idx.x, idx.y, idx.z, idx.w};
    const float wa[4] = {wv.x, wv.y, wv.z, wv.w};
#pragma unroll
    for (int c = 0; c < 4; ++c) {
      const uint4 u = *(const uint4*)&vb[(size_t)ia[c] * kC];
      const float w = wa[c];
      acc[0] = fmaf(w, uasf(u.x << 16), acc[0]);
      acc[1] = fmaf(w, uasf(u.x & 0xffff0000u), acc[1]);
      acc[2] = fmaf(w, uasf(u.y << 16), acc[2]);
      acc[3] = fmaf(w, uasf(u.y & 0xffff0000u), acc[3]);
      acc[4] = fmaf(w, uasf(u.z << 16), acc[4]);
      acc[5] = fmaf(w, uasf(u.z & 0xffff0000u), acc[5]);
      acc[6] = fmaf(w, uasf(u.w << 16), acc[6]);
      acc[7] = fmaf(w, uasf(u.w & 0xffff0000u), acc[7]);
    }
  }
  const int m = m0 + q_l;
  short8 outv;
#pragma unroll
  for (int e = 0; e < 8; ++e) outv[e] = (short)f2bf(acc[e]);
  *(short8*)&AO[(size_t)m * kC + h * 64 + c8] = outv;
}

// -----------------------------------------------------------------------------
extern "C" void kernel_launch(void* const* d_in, const int* in_sizes, int n_in,
                              void* d_out, int out_size, void* d_ws, size_t ws_size,
                              hipStream_t stream) {
  const float* x1 = (const float*)d_in[0];
  const float* x2 = (const float*)d_in[1];
  const float* ln1_g = (const float*)d_in[2];
  const float* ln1_b = (const float*)d_in[3];
  const float* ln2_g = (const float*)d_in[4];
  const float* ln2_b = (const float*)d_in[5];
  const float* pos_scale = (const float*)d_in[6];
  const float* W_off = (const float*)d_in[7];
  const float* b_off = (const float*)d_in[8];
  const float* W_att = (const float*)d_in[9];
  const float* b_att = (const float*)d_in[10];
  const float* W_val = (const float*)d_in[11];
  const float* b_val = (const float*)d_in[12];
  const float* W_out = (const float*)d_in[13];
  const float* b_out = (const float*)d_in[14];
  float* out = (float*)d_out;

  char* ws = (char*)d_ws;
  const size_t plane2 = (size_t)kM * kC * sizeof(unsigned short);  // 16 MiB
  unsigned short* Qb   = (unsigned short*)(ws);
  unsigned short* LN2b = (unsigned short*)(ws + plane2);
  unsigned short* Vb   = (unsigned short*)(ws + 2 * plane2);
  unsigned short* AOb  = (unsigned short*)(ws + 3 * plane2);
  float* RAW           = (float*)(ws + 4 * plane2);
  unsigned short* WvT  = (unsigned short*)(ws + 4 * plane2 + (size_t)kM * 48 * 4);
  unsigned short* WoT  = WvT + 65536;
  unsigned short* WoaT = WoT + 65536;

  prep_weights_kernel<<<256, 256, 0, stream>>>(W_val, W_out, W_off, W_att, WvT, WoT, WoaT);
  ln_transpose_kernel<<<1024, 256, 0, stream>>>(x1, ln1_g, ln1_b, pos_scale, Qb, 1);
  ln_transpose_kernel<<<1024, 256, 0, stream>>>(x2, ln2_g, ln2_b, pos_scale, LN2b, 0);
  gemm_val_kernel<<<dim3(kM / 128, 2), 256, 0, stream>>>(LN2b, WvT, b_val, Vb);
  gemm_offatt_kernel<<<kM / 128, 256, 0, stream>>>(Qb, WoaT, b_off, b_att, RAW);
  sample_kernel<<<kM / 8, 256, 0, stream>>>(RAW, Vb, AOb);
  gemm_out_kernel<<<dim3(kM / 128, 2), 256, 0, stream>>>(WoT, AOb, b_out, x2, out);
}